// Round 9
// baseline (381.060 us; speedup 1.0000x reference)
//
#include <hip/hip_runtime.h>
#include <hip/hip_bf16.h>

// GNN layer: out = relu( D^-1/2 (A+I) D^-1/2 (X @ W) )
// B=16, N=2048, F=64, U=64. A is EXACTLY binary ((uniform<0.01).astype(f32)).
//
//   K12 (wave-per-row, 1 row/wave, NO grid-stride): per row i --
//     issue wcol (W column u=lane, 64 VGPRs), X[i,lane], 8x16B nontemporal
//     A-row loads; compute X_i.W via v_readlane+fma UNDER the A latency
//     (waits only vmcnt(8)); then ballot-compact A nonzeros -> idx, cnt;
//     d_i = rsqrt(1+cnt); T'[i] = d_i*(X_i.W).  VALU-only dot, no LDS.
//   K3 (wave-per-row): out_i = relu(d_i*(T'_i + sum_j T'_j)); 2-quad-deep
//     (8 gathers in flight) wave-uniform idx pipeline; nontemporal out.
//   Shared XCD-affinity row map keeps each XCD's T' gathers in its 4MB L2.
//   Rows with cnt>cap fall back to a dense re-read of their A row in K3.

#define NB     16
#define NN     2048
#define NF     64
#define NU     64
#define NROWS  (NB * NN)          // 32768
#define NGRP   (NROWS / 4)        // 8192 groups of 4 rows (one per wave)

typedef unsigned int uint;
typedef uint vuint4 __attribute__((ext_vector_type(4)));

__device__ __forceinline__ int map_row(int g, int wid) {
    // XCD x (= g%8) handles batches {x, x+8}: T' gather working set ~1MB/XCD
    // stays inside the private 4MB L2. Performance heuristic only.
    const int x = g & 7, s = g >> 3;            // s in [0,1024)
    const int batch = x + ((s >> 9) << 3);      // s<512 -> batch x, else x+8
    const int grp = s & 511;
    return (batch << 11) + (grp << 2) + wid;
}

__global__ __launch_bounds__(256) void k12_scan_transform(
    const float* __restrict__ X, const float* __restrict__ A,
    const float* __restrict__ W, float* __restrict__ Tp,
    float* __restrict__ d, int* __restrict__ counts,
    int* __restrict__ idx, int cap)
{
    const int t = threadIdx.x, wid = t >> 6, lane = t & 63;   // lane = u
    const int row = map_row(blockIdx.x, wid);

    // Issue order matters: wcol+xv first, A-row after -> the dot can start
    // at vmcnt(8) while the 8 A-loads are still in flight.
    float wcol[NF];                                // W L1/L2-resident (16KB)
    #pragma unroll
    for (int f = 0; f < NF; ++f) wcol[f] = W[f * NU + lane];
    const float xv = X[(size_t)row * NF + lane];   // lane holds X[row,lane]

    const uint* Arow = reinterpret_cast<const uint*>(A + (size_t)row * NN);
    vuint4 a[8];                                   // whole row in flight (8KB)
    #pragma unroll
    for (int c = 0; c < 8; ++c)
        a[c] = __builtin_nontemporal_load(
            reinterpret_cast<const vuint4*>(Arow) + c * 64 + lane);

    // X_i . W under the A latency: VALU-only (v_readlane + v_fmac).
    float acc = 0.f;
    #pragma unroll
    for (int f = 0; f < NF; ++f) {
        const float xf = __int_as_float(
            __builtin_amdgcn_readlane(__float_as_int(xv), f));
        acc += xf * wcol[f];
    }

    // Consume A: ballot-compacted column indices + count.
    const unsigned long long lmask_lt = (lane == 63) ? 0x7fffffffffffffffull
                                                     : ((1ull << lane) - 1ull);
    const size_t base = (size_t)row * cap;
    int cnt = 0;
    #pragma unroll
    for (int c = 0; c < 8; ++c) {
        #pragma unroll
        for (int e = 0; e < 4; ++e) {
            const bool nz = (a[c][e] != 0u);        // binary A: bits!=0 <=> 1.0f
            const unsigned long long m = __ballot(nz);
            if (m) {                                // wave-uniform branch
                if (nz) {
                    const int slot = cnt + __popcll(m & lmask_lt);
                    if (slot < cap)
                        idx[base + slot] = ((c * 64 + lane) << 2) + e;
                }
                cnt += __popcll(m);                 // uniform across wave
            }
        }
    }

    const float di = rsqrtf((float)cnt + 1.0f);     // +I; always > 0
    if (lane == 0) { d[row] = di; counts[row] = cnt; }
    Tp[(size_t)row * NU + lane] = acc * di;         // keep L2-resident for K3
}

__global__ __launch_bounds__(256) void k3_aggregate(
    const float* __restrict__ A, const float* __restrict__ Tp,
    const float* __restrict__ d, const int* __restrict__ counts,
    const int* __restrict__ idx, float* __restrict__ out, int cap)
{
    const int t = threadIdx.x, wid = t >> 6, lane = t & 63;   // lane = u
    const int row = map_row(blockIdx.x, wid);      // (b*N + i)
    const int b   = row >> 11;                     // N = 2048
    const float* Tb = Tp + (((size_t)b) << 11) * NU;

    float a0 = Tp[(size_t)row * NU + lane];        // self-loop term T'[i,u]
    float a1 = 0.f, a2 = 0.f, a3 = 0.f;
    const int cnt = counts[row];
    if (cnt <= cap) {
        const size_t base = (size_t)row * cap;     // cap%4==0 -> 16B aligned
        const int4* q4 = reinterpret_cast<const int4*>(idx + base);
        const int nfull = cnt >> 2;
        int q = 0;
        int4 qa, qb;
        if (nfull > 0) qa = q4[0];
        if (nfull > 1) qb = q4[1];
        for (; q + 2 <= nfull; q += 2) {           // 8 gathers in flight
            const int4 c0 = qa, c1 = qb;
            if (q + 2 < nfull) qa = q4[q + 2];     // prefetch next pair
            if (q + 3 < nfull) qb = q4[q + 3];
            a0 += Tb[((size_t)(uint)c0.x << 6) + lane];
            a1 += Tb[((size_t)(uint)c0.y << 6) + lane];
            a2 += Tb[((size_t)(uint)c0.z << 6) + lane];
            a3 += Tb[((size_t)(uint)c0.w << 6) + lane];
            a0 += Tb[((size_t)(uint)c1.x << 6) + lane];
            a1 += Tb[((size_t)(uint)c1.y << 6) + lane];
            a2 += Tb[((size_t)(uint)c1.z << 6) + lane];
            a3 += Tb[((size_t)(uint)c1.w << 6) + lane];
        }
        if (q < nfull) {                           // odd leftover quad
            a0 += Tb[((size_t)(uint)qa.x << 6) + lane];
            a1 += Tb[((size_t)(uint)qa.y << 6) + lane];
            a2 += Tb[((size_t)(uint)qa.z << 6) + lane];
            a3 += Tb[((size_t)(uint)qa.w << 6) + lane];
        }
        for (int k = nfull << 2; k < cnt; ++k)     // <=3 tail neighbors
            a1 += Tb[((size_t)(uint)idx[base + k] << 6) + lane];
    } else {                                        // overflow: dense re-read
        const float* Arow = A + (size_t)row * NN;
        for (int j = 0; j < NN; ++j)
            if (Arow[j] != 0.f) a1 += Tb[((size_t)j << 6) + lane];
    }
    const float r = d[row] * ((a0 + a1) + (a2 + a3));
    __builtin_nontemporal_store(r > 0.f ? r : 0.f,
                                &out[(size_t)row * NU + lane]);
}

extern "C" void kernel_launch(void* const* d_in, const int* in_sizes, int n_in,
                              void* d_out, int out_size, void* d_ws, size_t ws_size,
                              hipStream_t stream)
{
    const float* X = (const float*)d_in[0];   // [B,N,F]
    const float* A = (const float*)d_in[1];   // [B,N,N]
    const float* W = (const float*)d_in[2];   // [F,U]
    float* out = (float*)d_out;               // [B,N,U]

    char* ws = (char*)d_ws;
    float* Tp     = (float*)ws;                                   // 8 MB
    float* dvec   = (float*)(ws + (size_t)NROWS * NU * 4);        // 128 KB
    int*   counts = (int*)  (ws + (size_t)NROWS * NU * 4 + (size_t)NROWS * 4);
    int*   idx    = (int*)  (ws + (size_t)NROWS * NU * 4 + 2ull * NROWS * 4);

    const size_t fixed = (size_t)NROWS * NU * 4 + 2ull * NROWS * 4;
    int cap = 0;
    if (ws_size > fixed) {
        size_t c = (ws_size - fixed) / ((size_t)NROWS * sizeof(int));
        cap = (int)(c < 128 ? c : 128);
        cap &= ~3;                                // int4-aligned per-row base
    }

    k12_scan_transform<<<NGRP, 256, 0, stream>>>(X, A, W, Tp, dvec, counts, idx, cap);
    k3_aggregate<<<NGRP, 256, 0, stream>>>(A, Tp, dvec, counts, idx, out, cap);
}

// Round 10
// 380.199 us; speedup vs baseline: 1.0023x; 1.0023x over previous
//
#include <hip/hip_runtime.h>
#include <hip/hip_bf16.h>

// GNN layer: out = relu( D^-1/2 (A+I) D^-1/2 (X @ W) )
// B=16, N=2048, F=64, U=64. A is EXACTLY binary ((uniform<0.01).astype(f32)).
//
//   K1  (wave-per-row): branchless bitmap pass over A (nontemporal):
//       lane l builds a 32-bit word of its own nz flags (bit p=c*4+e <->
//       column j = c*256 + l*4 + e), one coalesced store. NO ballots,
//       NO branches, NO scatter in the 256MB-stream kernel.
//   K1b (wave-per-row, 8MB): bitmap -> CSR idx + counts + d=rsqrt(1+cnt).
//       popc + 6-step shfl prefix scan; per-lane short bit-scan scatter.
//   K2  (wave-per-row, x4 grid-stride): T'[i,u]=d_i*sum_f X[i,f]*W[f,u];
//       W column in 64 VGPRs, X broadcast via v_readlane (VALU-only loop).
//   K3  (wave-per-row): out_i = relu(d_i*(T'_i + sum_j T'_j)); quad-unrolled
//       wave-uniform idx loads + 1-quad prefetch; nontemporal out stores.
//   Shared XCD-affinity row map; dense re-read fallback if cnt>cap.

#define NB     16
#define NN     2048
#define NF     64
#define NU     64
#define NROWS  (NB * NN)          // 32768
#define NGRP   (NROWS / 4)        // 8192 groups of 4 rows (one per wave)
#define K2BLK  2048
#define K2IT   (NGRP / K2BLK)     // 4

typedef unsigned int uint;
typedef uint vuint4 __attribute__((ext_vector_type(4)));

__device__ __forceinline__ int map_row(int g, int wid) {
    // XCD x (= g%8) handles batches {x, x+8}: T' gather working set ~1MB/XCD
    // stays inside the private 4MB L2. Performance heuristic only.
    const int x = g & 7, s = g >> 3;            // s in [0,1024)
    const int batch = x + ((s >> 9) << 3);      // s<512 -> batch x, else x+8
    const int grp = s & 511;
    return (batch << 11) + (grp << 2) + wid;
}

__global__ __launch_bounds__(256) void k1_bitmap(
    const float* __restrict__ A, uint* __restrict__ bm)
{
    const int t = threadIdx.x, wid = t >> 6, lane = t & 63;
    const int row = map_row(blockIdx.x, wid);
    const uint* Arow = reinterpret_cast<const uint*>(A + (size_t)row * NN);
    vuint4 a[8];                                   // whole row in flight (8KB/wave)
    #pragma unroll
    for (int c = 0; c < 8; ++c)
        a[c] = __builtin_nontemporal_load(
            reinterpret_cast<const vuint4*>(Arow) + c * 64 + lane);

    uint word = 0u;                                // bit p=c*4+e: col c*256+lane*4+e
    #pragma unroll
    for (int c = 0; c < 8; ++c) {
        #pragma unroll
        for (int e = 0; e < 4; ++e)
            word |= (a[c][e] != 0u) ? (1u << (c * 4 + e)) : 0u;
    }
    bm[(size_t)row * 64 + lane] = word;            // coalesced 256B per wave
}

__global__ __launch_bounds__(256) void k1b_decode(
    const uint* __restrict__ bm, float* __restrict__ d,
    int* __restrict__ counts, int* __restrict__ idx, int cap)
{
    const int t = threadIdx.x, wid = t >> 6, lane = t & 63;
    const int row = map_row(blockIdx.x, wid);
    uint w = bm[(size_t)row * 64 + lane];
    const int nl = __popc(w);
    int incl = nl;                                 // 6-step inclusive scan
    #pragma unroll
    for (int o = 1; o < 64; o <<= 1) {
        const int v = __shfl_up(incl, o);
        incl = (lane >= o) ? incl + v : incl;
    }
    int p = incl - nl;                             // exclusive prefix = my slot base
    const size_t base = (size_t)row * cap;
    while (w) {                                    // <= ~4 bits per lane (1% density)
        const int b = __builtin_ctz(w); w &= w - 1;
        const int j = ((b >> 2) << 8) + (lane << 2) + (b & 3);
        if (p < cap) idx[base + p] = j;            // order within row irrelevant
        ++p;
    }
    if (lane == 63) {
        counts[row] = incl;                        // total nnz of the row
        d[row]      = rsqrtf((float)incl + 1.0f);  // +I; always > 0
    }
}

__global__ __launch_bounds__(256) void k2_transform_scale(
    const float* __restrict__ X, const float* __restrict__ W,
    const float* __restrict__ d, float* __restrict__ Tp)
{
    const int t = threadIdx.x, wid = t >> 6, lane = t & 63;   // lane = u
    float wcol[NF];                                // W column in 64 VGPRs
    #pragma unroll
    for (int f = 0; f < NF; ++f) wcol[f] = W[f * NU + lane];

    #pragma unroll
    for (int it = 0; it < K2IT; ++it) {            // amortize wcol over 4 rows
        const int g   = blockIdx.x + it * K2BLK;   // g%8 invariant (K2BLK%8==0)
        const int row = map_row(g, wid);
        const float xv = X[(size_t)row * NF + lane];
        const float dr = d[row];
        float acc = 0.f;
        #pragma unroll
        for (int f = 0; f < NF; ++f) {             // VALU-only inner loop
            const float xf = __int_as_float(
                __builtin_amdgcn_readlane(__float_as_int(xv), f));
            acc += xf * wcol[f];
        }
        Tp[(size_t)row * NU + lane] = acc * dr;
    }
}

__global__ __launch_bounds__(256) void k3_aggregate(
    const float* __restrict__ A, const float* __restrict__ Tp,
    const float* __restrict__ d, const int* __restrict__ counts,
    const int* __restrict__ idx, float* __restrict__ out, int cap)
{
    const int t = threadIdx.x, wid = t >> 6, lane = t & 63;   // lane = u
    const int row = map_row(blockIdx.x, wid);      // (b*N + i)
    const int b   = row >> 11;                     // N = 2048
    const float* Tb = Tp + (((size_t)b) << 11) * NU;

    float a0 = Tp[(size_t)row * NU + lane];        // self-loop term T'[i,u]
    float a1 = 0.f;
    const int cnt = counts[row];
    if (cnt <= cap) {
        const size_t base = (size_t)row * cap;     // cap%4==0 -> 16B aligned
        const int4* q4 = reinterpret_cast<const int4*>(idx + base);
        const int nfull = cnt >> 2;
        if (nfull > 0) {
            int4 qq = q4[0];                       // wave-uniform 16B load
            for (int q = 0; q < nfull; ++q) {
                const int4 cur = qq;
                if (q + 1 < nfull) qq = q4[q + 1]; // prefetch next quad
                const float t0 = Tb[((size_t)(uint)cur.x << 6) + lane];
                const float t1 = Tb[((size_t)(uint)cur.y << 6) + lane];
                const float t2 = Tb[((size_t)(uint)cur.z << 6) + lane];
                const float t3 = Tb[((size_t)(uint)cur.w << 6) + lane];
                a0 += t0 + t2;
                a1 += t1 + t3;
            }
        }
        for (int k = nfull << 2; k < cnt; ++k)     // <=3 tail neighbors
            a1 += Tb[((size_t)(uint)idx[base + k] << 6) + lane];
    } else {                                        // overflow: dense re-read
        const float* Arow = A + (size_t)row * NN;
        for (int j = 0; j < NN; ++j)
            if (Arow[j] != 0.f) a1 += Tb[((size_t)j << 6) + lane];
    }
    const float r = d[row] * (a0 + a1);
    __builtin_nontemporal_store(r > 0.f ? r : 0.f,
                                &out[(size_t)row * NU + lane]);
}

extern "C" void kernel_launch(void* const* d_in, const int* in_sizes, int n_in,
                              void* d_out, int out_size, void* d_ws, size_t ws_size,
                              hipStream_t stream)
{
    const float* X = (const float*)d_in[0];   // [B,N,F]
    const float* A = (const float*)d_in[1];   // [B,N,N]
    const float* W = (const float*)d_in[2];   // [F,U]
    float* out = (float*)d_out;               // [B,N,U]

    char* ws = (char*)d_ws;
    size_t off = 0;
    float* Tp     = (float*)(ws + off); off += (size_t)NROWS * NU * 4;   // 8 MB
    float* dvec   = (float*)(ws + off); off += (size_t)NROWS * 4;        // 128 KB
    int*   counts = (int*)  (ws + off); off += (size_t)NROWS * 4;        // 128 KB
    uint*  bm     = (uint*) (ws + off); off += (size_t)NROWS * 64 * 4;   // 8 MB
    int*   idx    = (int*)  (ws + off);

    int cap = 0;
    if (ws_size > off) {
        size_t c = (ws_size - off) / ((size_t)NROWS * sizeof(int));
        cap = (int)(c < 128 ? c : 128);
        cap &= ~3;                                // int4-aligned per-row base
    }

    k1_bitmap   <<<NGRP, 256, 0, stream>>>(A, bm);
    k1b_decode  <<<NGRP, 256, 0, stream>>>(bm, dvec, counts, idx, cap);
    k2_transform_scale<<<K2BLK, 256, 0, stream>>>(X, W, dvec, Tp);
    k3_aggregate<<<NGRP, 256, 0, stream>>>(A, Tp, dvec, counts, idx, out, cap);
}

// Round 11
// 369.304 us; speedup vs baseline: 1.0318x; 1.0295x over previous
//
#include <hip/hip_runtime.h>
#include <hip/hip_bf16.h>

// GNN layer: out = relu( D^-1/2 (A+I) D^-1/2 (X @ W) )
// B=16, N=2048, F=64, U=64. A is EXACTLY binary ((uniform<0.01).astype(f32)).
// BEST-MEASURED CONFIG (R8, 373us). Structure:
//   K1 (wave-per-row): nontemporal pass over A -> counts, d=rsqrt(1+cnt),
//       ballot-compacted column indices into d_ws.   [~A-read floor]
//   K2 (wave-per-row, x4 grid-stride): T'[i,u]=d_i*sum_f X[i,f]*W[f,u].
//       W column in 64 VGPRs, X broadcast via v_readlane -- VALU-only loop.
//   K3 (wave-per-row): out_i = relu(d_i*(T'_i + sum_j T'_j)); 2-quad-deep
//       (8 gathers in flight) wave-uniform idx pipeline; nontemporal out.
//   Shared XCD-affinity row map keeps each XCD's T' gathers in its 4MB L2.
//   Rows with cnt>cap fall back to a dense re-read of their A row in K3.

#define NB     16
#define NN     2048
#define NF     64
#define NU     64
#define NROWS  (NB * NN)          // 32768
#define NGRP   (NROWS / 4)        // 8192 groups of 4 rows (one per wave)
#define K2BLK  2048
#define K2IT   (NGRP / K2BLK)     // 4

typedef unsigned int uint;
typedef uint vuint4 __attribute__((ext_vector_type(4)));

__device__ __forceinline__ int map_row(int g, int wid) {
    // XCD x (= g%8) handles batches {x, x+8}: T' gather working set ~1MB/XCD
    // stays inside the private 4MB L2. Performance heuristic only.
    const int x = g & 7, s = g >> 3;            // s in [0,1024)
    const int batch = x + ((s >> 9) << 3);      // s<512 -> batch x, else x+8
    const int grp = s & 511;
    return (batch << 11) + (grp << 2) + wid;
}

__global__ __launch_bounds__(256) void k1_rowsum_compact(
    const float* __restrict__ A, float* __restrict__ d,
    int* __restrict__ counts, int* __restrict__ idx, int cap)
{
    const int t = threadIdx.x, wid = t >> 6, lane = t & 63;
    const int row = map_row(blockIdx.x, wid);
    const uint* Arow = reinterpret_cast<const uint*>(A + (size_t)row * NN);
    const unsigned long long lmask_lt = (lane == 63) ? 0x7fffffffffffffffull
                                                     : ((1ull << lane) - 1ull);
    vuint4 a[8];                                   // whole row in flight
    #pragma unroll
    for (int c = 0; c < 8; ++c)
        a[c] = __builtin_nontemporal_load(
            reinterpret_cast<const vuint4*>(Arow) + c * 64 + lane);

    const size_t base = (size_t)row * cap;
    int cnt = 0;
    #pragma unroll
    for (int c = 0; c < 8; ++c) {
        #pragma unroll
        for (int e = 0; e < 4; ++e) {
            const bool nz = (a[c][e] != 0u);        // binary A: bits!=0 <=> 1.0f
            const unsigned long long m = __ballot(nz);
            if (m) {                                // wave-uniform branch
                if (nz) {
                    const int slot = cnt + __popcll(m & lmask_lt);
                    if (slot < cap)
                        idx[base + slot] = ((c * 64 + lane) << 2) + e;
                }
                cnt += __popcll(m);                 // uniform across wave
            }
        }
    }
    if (lane == 0) {
        d[row]      = rsqrtf((float)cnt + 1.0f);    // +I; always > 0
        counts[row] = cnt;
    }
}

__global__ __launch_bounds__(256) void k2_transform_scale(
    const float* __restrict__ X, const float* __restrict__ W,
    const float* __restrict__ d, float* __restrict__ Tp)
{
    const int t = threadIdx.x, wid = t >> 6, lane = t & 63;   // lane = u
    // W column u=lane in 64 VGPRs; coalesced 256B per f; L1/L2-resident (16KB).
    float wcol[NF];
    #pragma unroll
    for (int f = 0; f < NF; ++f) wcol[f] = W[f * NU + lane];

    #pragma unroll
    for (int it = 0; it < K2IT; ++it) {            // amortize wcol over 4 rows
        const int g   = blockIdx.x + it * K2BLK;   // g%8 invariant (K2BLK%8==0)
        const int row = map_row(g, wid);
        const float xv = X[(size_t)row * NF + lane];   // lane holds X[row,lane]
        const float dr = d[row];
        float acc = 0.f;
        #pragma unroll
        for (int f = 0; f < NF; ++f) {             // VALU-only inner loop
            const float xf = __int_as_float(
                __builtin_amdgcn_readlane(__float_as_int(xv), f));
            acc += xf * wcol[f];                   // v_fmac with SGPR operand
        }
        Tp[(size_t)row * NU + lane] = acc * dr;
    }
}

__global__ __launch_bounds__(256) void k3_aggregate(
    const float* __restrict__ A, const float* __restrict__ Tp,
    const float* __restrict__ d, const int* __restrict__ counts,
    const int* __restrict__ idx, float* __restrict__ out, int cap)
{
    const int t = threadIdx.x, wid = t >> 6, lane = t & 63;   // lane = u
    const int row = map_row(blockIdx.x, wid);      // (b*N + i)
    const int b   = row >> 11;                     // N = 2048
    const float* Tb = Tp + (((size_t)b) << 11) * NU;

    float a0 = Tp[(size_t)row * NU + lane];        // self-loop term T'[i,u]
    float a1 = 0.f, a2 = 0.f, a3 = 0.f;
    const int cnt = counts[row];
    if (cnt <= cap) {
        const size_t base = (size_t)row * cap;     // cap%4==0 -> 16B aligned
        const int4* q4 = reinterpret_cast<const int4*>(idx + base);
        const int nfull = cnt >> 2;
        int q = 0;
        int4 qa, qb;
        if (nfull > 0) qa = q4[0];
        if (nfull > 1) qb = q4[1];
        for (; q + 2 <= nfull; q += 2) {           // 8 gathers in flight
            const int4 c0 = qa, c1 = qb;
            if (q + 2 < nfull) qa = q4[q + 2];     // prefetch next pair
            if (q + 3 < nfull) qb = q4[q + 3];
            a0 += Tb[((size_t)(uint)c0.x << 6) + lane];
            a1 += Tb[((size_t)(uint)c0.y << 6) + lane];
            a2 += Tb[((size_t)(uint)c0.z << 6) + lane];
            a3 += Tb[((size_t)(uint)c0.w << 6) + lane];
            a0 += Tb[((size_t)(uint)c1.x << 6) + lane];
            a1 += Tb[((size_t)(uint)c1.y << 6) + lane];
            a2 += Tb[((size_t)(uint)c1.z << 6) + lane];
            a3 += Tb[((size_t)(uint)c1.w << 6) + lane];
        }
        if (q < nfull) {                           // odd leftover quad
            a0 += Tb[((size_t)(uint)qa.x << 6) + lane];
            a1 += Tb[((size_t)(uint)qa.y << 6) + lane];
            a2 += Tb[((size_t)(uint)qa.z << 6) + lane];
            a3 += Tb[((size_t)(uint)qa.w << 6) + lane];
        }
        for (int k = nfull << 2; k < cnt; ++k)     // <=3 tail neighbors
            a1 += Tb[((size_t)(uint)idx[base + k] << 6) + lane];
    } else {                                        // overflow: dense re-read
        const float* Arow = A + (size_t)row * NN;
        for (int j = 0; j < NN; ++j)
            if (Arow[j] != 0.f) a1 += Tb[((size_t)j << 6) + lane];
    }
    const float r = d[row] * ((a0 + a1) + (a2 + a3));
    __builtin_nontemporal_store(r > 0.f ? r : 0.f,
                                &out[(size_t)row * NU + lane]);
}

extern "C" void kernel_launch(void* const* d_in, const int* in_sizes, int n_in,
                              void* d_out, int out_size, void* d_ws, size_t ws_size,
                              hipStream_t stream)
{
    const float* X = (const float*)d_in[0];   // [B,N,F]
    const float* A = (const float*)d_in[1];   // [B,N,N]
    const float* W = (const float*)d_in[2];   // [F,U]
    float* out = (float*)d_out;               // [B,N,U]

    char* ws = (char*)d_ws;
    float* Tp     = (float*)ws;                                   // 8 MB
    float* dvec   = (float*)(ws + (size_t)NROWS * NU * 4);        // 128 KB
    int*   counts = (int*)  (ws + (size_t)NROWS * NU * 4 + (size_t)NROWS * 4);
    int*   idx    = (int*)  (ws + (size_t)NROWS * NU * 4 + 2ull * NROWS * 4);

    const size_t fixed = (size_t)NROWS * NU * 4 + 2ull * NROWS * 4;
    int cap = 0;
    if (ws_size > fixed) {
        size_t c = (ws_size - fixed) / ((size_t)NROWS * sizeof(int));
        cap = (int)(c < 128 ? c : 128);
        cap &= ~3;                                // int4-aligned per-row base
    }

    k1_rowsum_compact<<<NGRP, 256, 0, stream>>>(A, dvec, counts, idx, cap);
    k2_transform_scale<<<K2BLK, 256, 0, stream>>>(X, W, dvec, Tp);
    k3_aggregate<<<NGRP, 256, 0, stream>>>(A, Tp, dvec, counts, idx, out, cap);
}